// Round 15
// baseline (79.982 us; speedup 1.0000x reference)
//
#include <hip/hip_runtime.h>
#include <math.h>

#define NPIX 784
#define NCLS 10
#define ROWS 16           // rows per block (8 lane-groups x 2 rows)
#define BLOCK 256

// Circuit identity: all gates are RY (no entanglers); RY on one wire compose
// additively, so <Z_w> = cos(x_w + sum_l theta[l][w]).
// feats[f], f = patch*4 + w; wire w reads pixel (2pr + (w>>1), 2pc + (w&1)).
// R12 change vs R7: NO LDS, NO barrier — W is read directly through L1/L2.
// All 8 lane-groups of a block read identical W addresses (they differ only
// in batch row), and W is 31 KB ~ L1-resident, so the inner-loop W reads are
// near-pure L1 hits; this deletes the staging prologue + __syncthreads.
__global__ __launch_bounds__(256)
void quanv_fused_kernel(const float* __restrict__ x,
                        const float* __restrict__ theta,
                        const float* __restrict__ W,
                        const float* __restrict__ bias,
                        float* __restrict__ out) {
    int tid = threadIdx.x;

    // per-wire angle offsets (L1-cached scalar reads)
    float t0 = theta[0] + theta[4] + theta[8];
    float t1 = theta[1] + theta[5] + theta[9];
    float t2 = theta[2] + theta[6] + theta[10];
    float t3 = theta[3] + theta[7] + theta[11];

    int tx = tid & 31;
    int g  = tid >> 5;                      // 0..7
    int row0 = blockIdx.x * ROWS + g * 2;
    const float* xr0 = x + (size_t)row0 * NPIX;
    const float* xr1 = xr0 + NPIX;

    float acc0[NCLS], acc1[NCLS];
#pragma unroll
    for (int k = 0; k < NCLS; ++k) { acc0[k] = 0.f; acc1[k] = 0.f; }

#pragma unroll
    for (int s = 0; s < 7; ++s) {           // 196 patches: 6 full + 4-lane tail
        int p = tx + (s << 5);
        bool active = (s < 6) | (tx < 4);
        if (active) {
            int pr = p / 14;
            int pc = p - pr * 14;
            int off0 = pr * 56 + pc * 2;    // pixel idx of (2pr, 2pc)
            int off1 = off0 + 28;           // row 2pr+1
            float2 a0 = *reinterpret_cast<const float2*>(xr0 + off0);
            float2 b0 = *reinterpret_cast<const float2*>(xr0 + off1);
            float2 a1 = *reinterpret_cast<const float2*>(xr1 + off0);
            float2 b1 = *reinterpret_cast<const float2*>(xr1 + off1);
            float f00 = __cosf(a0.x + t0), f01 = __cosf(a0.y + t1);
            float f02 = __cosf(b0.x + t2), f03 = __cosf(b0.y + t3);
            float f10 = __cosf(a1.x + t0), f11 = __cosf(a1.y + t1);
            float f12 = __cosf(b1.x + t2), f13 = __cosf(b1.y + t3);
#pragma unroll
            for (int k = 0; k < NCLS; ++k) {
                float4 wv = *reinterpret_cast<const float4*>(&W[k * NPIX + (p << 2)]);
                acc0[k] += f00 * wv.x + f01 * wv.y + f02 * wv.z + f03 * wv.w;
                acc1[k] += f10 * wv.x + f11 * wv.y + f12 * wv.z + f13 * wv.w;
            }
        }
    }

    // ---- 32-lane reduction (xor stays inside each row's lane group) ----
#pragma unroll
    for (int k = 0; k < NCLS; ++k) {
        float v0 = acc0[k], v1 = acc1[k];
        v0 += __shfl_xor(v0, 1);  v1 += __shfl_xor(v1, 1);
        v0 += __shfl_xor(v0, 2);  v1 += __shfl_xor(v1, 2);
        v0 += __shfl_xor(v0, 4);  v1 += __shfl_xor(v1, 4);
        v0 += __shfl_xor(v0, 8);  v1 += __shfl_xor(v1, 8);
        v0 += __shfl_xor(v0, 16); v1 += __shfl_xor(v1, 16);
        acc0[k] = v0; acc1[k] = v1;
    }

    // lane 0 -> row0, lane 16 -> row1 (both hold the full sums)
    if (tx == 0 || tx == 16) {
        const float* a = (tx == 0) ? acc0 : acc1;
        int row = (tx == 0) ? row0 : row0 + 1;
        float logits[NCLS];
        float m = -1e30f;
#pragma unroll
        for (int k = 0; k < NCLS; ++k) {
            logits[k] = a[k] + bias[k];
            m = fmaxf(m, logits[k]);
        }
        float sum = 0.f;
#pragma unroll
        for (int k = 0; k < NCLS; ++k) sum += expf(logits[k] - m);
        float lse = m + logf(sum);
#pragma unroll
        for (int k = 0; k < NCLS; ++k) out[row * NCLS + k] = logits[k] - lse;
    }
}

extern "C" void kernel_launch(void* const* d_in, const int* in_sizes, int n_in,
                              void* d_out, int out_size, void* d_ws, size_t ws_size,
                              hipStream_t stream) {
    const float* x     = (const float*)d_in[0];
    const float* theta = (const float*)d_in[1];
    const float* W     = (const float*)d_in[2];
    const float* bias  = (const float*)d_in[3];
    float* out = (float*)d_out;

    int B = in_sizes[0] / NPIX;          // 8192
    int grid = B / ROWS;                 // 512 blocks
    quanv_fused_kernel<<<grid, BLOCK, 0, stream>>>(x, theta, W, bias, out);
}